// Round 21
// baseline (381.643 us; speedup 1.0000x reference)
//
#include <hip/hip_runtime.h>
#include <hip/hip_bf16.h>
#include <cstdint>

#define BB 4
#define SS 2048
#define DD 1024
#define HH 16
#define DHH 64
#define DFFN 4096
#define MROWS (BB*SS)   // 8192

typedef __attribute__((ext_vector_type(8))) __bf16 v8bf;  // MFMA A/B operand (4 VGPRs)
typedef __attribute__((ext_vector_type(4))) float v4f;    // MFMA acc

static __device__ __forceinline__ unsigned short f2bf(float f) {
  unsigned u = __float_as_uint(f);
  u = (u + 0x7fffu + ((u >> 16) & 1u)) >> 16;  // RNE
  return (unsigned short)u;
}

static __device__ __forceinline__ float b2f(unsigned short u) {
  return __uint_as_float((unsigned)u << 16);
}

static __device__ __forceinline__ unsigned bf2bits(__hip_bfloat162 h) {
  union { __hip_bfloat162 h; unsigned u; } cv; cv.h = h; return cv.u;
}

// D = A(16x32)*B(32x16)+D. A-frag: lane holds A[lane&15][8*(lane>>4)+i];
// B-frag: B[8*(lane>>4)+i][lane&15]; D: col=lane&15, row=(lane>>4)*4+reg (m89-verified)
static __device__ __forceinline__ void mfma16(v4f& d, v8bf a, v8bf b) {
  d = __builtin_amdgcn_mfma_f32_16x16x32_bf16(a, b, d, 0, 0, 0);
}

// async global->LDS, 16B per lane; LDS dest = wave-uniform base + lane*16
static __device__ __forceinline__ void gload16(const void* g, void* l) {
  __builtin_amdgcn_global_load_lds(
      (const __attribute__((address_space(1))) unsigned int*)(unsigned long long)g,
      (__attribute__((address_space(3))) unsigned int*)(unsigned int)(unsigned long long)l,
      16, 0, 0);
}

// T1 XCD swizzle: hw dispatch index -> work id so each XCD (hw%8 under round-robin)
// gets a CONTIGUOUS work chunk (m204 bijective form; all our grids are %8==0).
// REGISTER MODEL (r16): unified VGPR pool = 512/SIMD; (512,N) caps waves at 512/N regs.
// SCHEDULE MODEL (r18): keep both GEMM operands double-buffered (stage >=1 phase
// before drain); single-buffering inserts an uncovered stall.
static __device__ __forceinline__ unsigned xcd_work(unsigned hw, unsigned nwg) {
  return (hw & 7u) * (nwg >> 3) + (hw >> 3);
}

// ---------------- prep kernels ----------------

__global__ __launch_bounds__(256) void pack_x_k(const float* __restrict__ x,
                                                unsigned short* __restrict__ xb) {
  int i = blockIdx.x * 256 + threadIdx.x;           // one float4 per thread
  float4 v = ((const float4*)x)[i];
  ushort4 o;
  o.x = f2bf(v.x); o.y = f2bf(v.y); o.z = f2bf(v.z); o.w = f2bf(v.w);
  ((ushort4*)xb)[i] = o;
}

// dst[c][r] = bf16(src[r][c]); src is R x C row-major, dst is C x R row-major
static __device__ __forceinline__ void transpose_tile(const float* __restrict__ src,
                                                      unsigned short* __restrict__ dst,
                                                      int R, int C, int rt, int ct) {
  __shared__ float tile[32][33];
  const int tx = threadIdx.x, ty = threadIdx.y;
  #pragma unroll
  for (int j = 0; j < 4; ++j)
    tile[ty + j * 8][tx] = src[(size_t)(rt + ty + j * 8) * C + ct + tx];
  __syncthreads();
  #pragma unroll
  for (int j = 0; j < 4; ++j)
    dst[(size_t)(ct + ty + j * 8) * R + rt + tx] = f2bf(tile[tx][ty + j * 8]);
}

__global__ __launch_bounds__(256) void transpose_k(const float* __restrict__ src,
                                                   unsigned short* __restrict__ dst,
                                                   int R, int C) {
  transpose_tile(src, dst, R, C, blockIdx.y * 32, blockIdx.x * 32);
}

// wq/wk/wv are [H][D][DH]; packed dst row c = w*1024 + h*64 + e, cols = d (K-contig)
__global__ __launch_bounds__(256) void transpose_qkv_k(const float* __restrict__ wq,
                                                       const float* __restrict__ wk,
                                                       const float* __restrict__ wv,
                                                       unsigned short* __restrict__ dst) {
  const int z = blockIdx.z;
  const int w = z >> 4, h = z & 15;
  const float* src = (w == 0) ? wq : ((w == 1) ? wk : wv);
  src += (size_t)h * DD * DHH;
  unsigned short* d = dst + (size_t)(w * DD + h * DHH) * DD;
  transpose_tile(src, d, DD, DHH, blockIdx.y * 32, blockIdx.x * 32);
}

// ---------------- shared GEMM epilogue ----------------
// MODE 1 (O-proj) and MODE 3 (FF2) emit bf16 residual terms (o0) — LN accumulates
// in f32; input perturbation ~2^-8 is normalized away (r20-validated).
template<int MODE>
static __device__ __forceinline__ void gemm_epi(
    const v4f& a4, int rb, int col, int N,
    const float* __restrict__ bias0, const float* __restrict__ bias1,
    const float* __restrict__ bias2,
    float* __restrict__ outF, unsigned short* __restrict__ o0,
    unsigned short* __restrict__ o1, unsigned short* __restrict__ o2) {
  if constexpr (MODE == 0) {
    const int seg = col >> 10, cc = col & 1023;
    const int h = cc >> 6, e = cc & 63;
    const float bias = (seg == 0) ? bias0[cc] : (seg == 1) ? bias1[cc] : bias2[cc];
    if (seg < 2) {           // q or k -> [B,H,S,DH]; q pre-scaled by log2e/8
      unsigned short* dst = (seg == 0) ? o0 : o1;
      const float scl = (seg == 0) ? 0.18033688f : 1.0f;   // 0.125 * log2(e)
      #pragma unroll
      for (int i = 0; i < 4; ++i) {
        const int row = rb + i, b = row >> 11, s = row & (SS - 1);
        dst[(((size_t)b * HH + h) * SS + s) * DHH + e] = f2bf((a4[i] + bias) * scl);
      }
    } else {                 // v -> transposed [B,H,DH,S]
      const int b = rb >> 11, s0q = rb & (SS - 1);
      ushort4 pv;
      pv.x = f2bf(a4[0] + bias);
      pv.y = f2bf(a4[1] + bias);
      pv.z = f2bf(a4[2] + bias);
      pv.w = f2bf(a4[3] + bias);
      *(ushort4*)&o2[(((size_t)b * HH + h) * DHH + e) * SS + s0q] = pv;
    }
  } else if constexpr (MODE == 1 || MODE == 3) {   // bf16 residual term
    const float bias = bias0[col];
    #pragma unroll
    for (int i = 0; i < 4; ++i)
      o0[(size_t)(rb + i) * N + col] = f2bf(a4[i] + bias);
  } else {  // MODE 2: relu -> bf16
    const float bias = bias0[col];
    #pragma unroll
    for (int i = 0; i < 4; ++i)
      o0[(size_t)(rb + i) * N + col] = f2bf(fmaxf(a4[i] + bias, 0.f));
  }
}

// ---------------- wide GEMM: 256x256, BK=64, 8 waves 2Mx4N (r9/r12/r14-validated) ----------------

template<int MODE>
__global__ __launch_bounds__(512, 2) void gemm_bt(
    const unsigned short* __restrict__ A, const unsigned short* __restrict__ Bt,
    const float* __restrict__ bias0, const float* __restrict__ bias1,
    const float* __restrict__ bias2,
    float* __restrict__ outF, unsigned short* __restrict__ o0,
    unsigned short* __restrict__ o1, unsigned short* __restrict__ o2,
    int M, int N, int K) {
  extern __shared__ __align__(16) char smem[];   // A 2x32K | B 2x32K
  const int tid = threadIdx.x;
  const int wid = tid >> 6, lane = tid & 63;
  const int l15 = lane & 15, kg = lane >> 4;
  const unsigned nwg = gridDim.x * gridDim.y;
  const unsigned work = xcd_work(blockIdx.y * gridDim.x + blockIdx.x, nwg);
  const int m0 = (int)(work / gridDim.x) * 256, n0 = (int)(work % gridDim.x) * 256;
  const int wm = (wid >> 2) * 128, wn = (wid & 3) * 64;

  const int sr8 = wid * 8 + (lane >> 3);
  const int sge = ((lane & 7) ^ ((lane >> 3) & 7)) << 3;
  const int swr = (l15 & 7) << 4;

  const int NK = K >> 6;
  v4f acc[8][4] = {};

  #define STA(q, kt, lb) gload16(A  + (size_t)(m0 + (q) * 64 + sr8) * K + (kt) * 64 + sge, \
                                 (lb) + (q) * 8192 + wid * 1024)
  #define STB(q, kt, lb) gload16(Bt + (size_t)(n0 + (q) * 64 + sr8) * K + (kt) * 64 + sge, \
                                 (lb) + (q) * 8192 + wid * 1024)

  {  // prologue
    char* A0b = smem;
    char* B0b = smem + 65536;
    STB(0, 0, B0b); STB(1, 0, B0b); STB(2, 0, B0b); STB(3, 0, B0b);
    STA(0, 0, A0b); STA(2, 0, A0b); STA(1, 0, A0b); STA(3, 0, A0b);
    asm volatile("s_waitcnt vmcnt(2)" ::: "memory");
    __builtin_amdgcn_s_barrier();
  }

  #pragma unroll 1
  for (int j = 0; j < NK; ++j) {
    char* Ac = smem + (j & 1) * 32768;
    char* Bc = smem + 65536 + (j & 1) * 32768;
    char* An = smem + ((j + 1) & 1) * 32768;
    char* Bn = smem + 65536 + ((j + 1) & 1) * 32768;
    const bool more = (j + 1 < NK);

    v8bf bf_[4][2], af01[4][2];
    #pragma unroll
    for (int nr = 0; nr < 4; ++nr)
      #pragma unroll
      for (int ks = 0; ks < 2; ++ks)
        bf_[nr][ks] = *(const v8bf*)(Bc + (wn + nr * 16 + l15) * 128 +
                                     (((ks * 4 + kg) << 4) ^ swr));
    #pragma unroll
    for (int mi = 0; mi < 4; ++mi)
      #pragma unroll
      for (int ks = 0; ks < 2; ++ks)
        af01[mi][ks] = *(const v8bf*)(Ac + (wm + mi * 16 + l15) * 128 +
                                      (((ks * 4 + kg) << 4) ^ swr));
    if (more) { STB(0, j + 1, Bn); STB(1, j + 1, Bn); STB(2, j + 1, Bn); STB(3, j + 1, Bn); }
    __builtin_amdgcn_s_setprio(1);
    #pragma unroll
    for (int mi = 0; mi < 2; ++mi)
      #pragma unroll
      for (int nr = 0; nr < 4; ++nr)
        #pragma unroll
        for (int ks = 0; ks < 2; ++ks)
          mfma16(acc[mi][nr], af01[mi][ks], bf_[nr][ks]);
    __builtin_amdgcn_s_setprio(0);
    __builtin_amdgcn_s_barrier();

    if (more) {
      STA(0, j + 1, An); STA(2, j + 1, An); STA(1, j + 1, An); STA(3, j + 1, An);
      asm volatile("s_waitcnt vmcnt(8)" ::: "memory");
    } else {
      asm volatile("s_waitcnt vmcnt(0)" ::: "memory");
    }
    __builtin_amdgcn_s_setprio(1);
    #pragma unroll
    for (int mi = 2; mi < 4; ++mi)
      #pragma unroll
      for (int nr = 0; nr < 4; ++nr)
        #pragma unroll
        for (int ks = 0; ks < 2; ++ks)
          mfma16(acc[mi][nr], af01[mi][ks], bf_[nr][ks]);
    __builtin_amdgcn_s_setprio(0);
    __builtin_amdgcn_s_barrier();

    v8bf af23[4][2];
    #pragma unroll
    for (int mi = 0; mi < 4; ++mi)
      #pragma unroll
      for (int ks = 0; ks < 2; ++ks)
        af23[mi][ks] = *(const v8bf*)(Ac + (wm + (mi + 4) * 16 + l15) * 128 +
                                      (((ks * 4 + kg) << 4) ^ swr));
    __builtin_amdgcn_s_setprio(1);
    #pragma unroll
    for (int mi = 0; mi < 2; ++mi)
      #pragma unroll
      for (int nr = 0; nr < 4; ++nr)
        #pragma unroll
        for (int ks = 0; ks < 2; ++ks)
          mfma16(acc[mi + 4][nr], af23[mi][ks], bf_[nr][ks]);
    __builtin_amdgcn_s_setprio(0);
    __builtin_amdgcn_s_barrier();

    if (more) asm volatile("s_waitcnt vmcnt(2)" ::: "memory");
    __builtin_amdgcn_s_setprio(1);
    #pragma unroll
    for (int mi = 2; mi < 4; ++mi)
      #pragma unroll
      for (int nr = 0; nr < 4; ++nr)
        #pragma unroll
        for (int ks = 0; ks < 2; ++ks)
          mfma16(acc[mi + 4][nr], af23[mi][ks], bf_[nr][ks]);
    __builtin_amdgcn_s_setprio(0);
    __builtin_amdgcn_s_barrier();
  }
  #undef STA
  #undef STB

  #pragma unroll
  for (int nr = 0; nr < 4; ++nr) {
    const int col = n0 + wn + nr * 16 + l15;
    #pragma unroll
    for (int mr = 0; mr < 8; ++mr)
      gemm_epi<MODE>(acc[mr][nr], m0 + wm + mr * 16 + kg * 4, col, N,
                     bias0, bias1, bias2, outF, o0, o1, o2);
  }
}

// ---------------- narrow GEMM: 256x128, BK=64, 8 waves 4Mx2N (r10/r12/r14-validated) ----------------

template<int MODE>
__global__ __launch_bounds__(512, 2) void gemm_bt_n(
    const unsigned short* __restrict__ A, const unsigned short* __restrict__ Bt,
    const float* __restrict__ bias0, const float* __restrict__ bias1,
    const float* __restrict__ bias2,
    float* __restrict__ outF, unsigned short* __restrict__ o0,
    unsigned short* __restrict__ o1, unsigned short* __restrict__ o2,
    int M, int N, int K) {
  extern __shared__ __align__(16) char smem[];   // A 2x32K @0 | B 2x16K @65536
  const int tid = threadIdx.x;
  const int wid = tid >> 6, lane = tid & 63;
  const int l15 = lane & 15, kg = lane >> 4;
  const unsigned nwg = gridDim.x * gridDim.y;
  const unsigned work = xcd_work(blockIdx.y * gridDim.x + blockIdx.x, nwg);
  const int m0 = (int)(work / gridDim.x) * 256, n0 = (int)(work % gridDim.x) * 128;
  const int wm = (wid >> 1) * 64, wn = (wid & 1) * 64;

  const int sr8 = wid * 8 + (lane >> 3);
  const int sge = ((lane & 7) ^ ((lane >> 3) & 7)) << 3;
  const int swr = (l15 & 7) << 4;

  const int NK = K >> 6;
  v4f acc[4][4] = {};

  #define STA(q, kt, lb) gload16(A  + (size_t)(m0 + (q) * 64 + sr8) * K + (kt) * 64 + sge, \
                                 (lb) + (q) * 8192 + wid * 1024)
  #define STB(q, kt, lb) gload16(Bt + (size_t)(n0 + (q) * 64 + sr8) * K + (kt) * 64 + sge, \
                                 (lb) + (q) * 8192 + wid * 1024)

  {  // prologue: kt0 into buf0, full drain
    char* A0b = smem;
    char* B0b = smem + 65536;
    STB(0, 0, B0b); STB(1, 0, B0b);
    STA(0, 0, A0b); STA(1, 0, A0b); STA(2, 0, A0b); STA(3, 0, A0b);
    asm volatile("s_waitcnt vmcnt(0)" ::: "memory");
    __builtin_amdgcn_s_barrier();
  }

  #pragma unroll 1
  for (int j = 0; j < NK; ++j) {
    char* Ac = smem + (j & 1) * 32768;
    char* Bc = smem + 65536 + (j & 1) * 16384;
    char* An = smem + ((j + 1) & 1) * 32768;
    char* Bn = smem + 65536 + ((j + 1) & 1) * 16384;
    const bool more = (j + 1 < NK);

    // ---- p0 ----
    v8bf bf_[4][2], af01[2][2];
    #pragma unroll
    for (int nr = 0; nr < 4; ++nr)
      #pragma unroll
      for (int ks = 0; ks < 2; ++ks)
        bf_[nr][ks] = *(const v8bf*)(Bc + (wn + nr * 16 + l15) * 128 +
                                     (((ks * 4 + kg) << 4) ^ swr));
    #pragma unroll
    for (int mi = 0; mi < 2; ++mi)
      #pragma unroll
      for (int ks = 0; ks < 2; ++ks)
        af01[mi][ks] = *(const v8bf*)(Ac + (wm + mi * 16 + l15) * 128 +
                                      (((ks * 4 + kg) << 4) ^ swr));
    if (more) {
      STB(0, j + 1, Bn); STB(1, j + 1, Bn);
      STA(0, j + 1, An); STA(1, j + 1, An); STA(2, j + 1, An); STA(3, j + 1, An);
    }
    __builtin_amdgcn_s_setprio(1);
    #pragma unroll
    for (int mi = 0; mi < 2; ++mi)
      #pragma unroll
      for (int nr = 0; nr < 4; ++nr)
        #pragma unroll
        for (int ks = 0; ks < 2; ++ks)
          mfma16(acc[mi][nr], af01[mi][ks], bf_[nr][ks]);
    __builtin_amdgcn_s_setprio(0);
    __builtin_amdgcn_s_barrier();

    // ---- p1 ----
    v8bf af23[2][2];
    #pragma unroll
    for (int mi = 0; mi < 2; ++mi)
      #pragma unroll
      for (int ks = 0; ks < 2; ++ks)
        af23[mi][ks] = *(const v8bf*)(Ac + (wm + (mi + 2) * 16 + l15) * 128 +
                                      (((ks * 4 + kg) << 4) ^ swr));
    __builtin_amdgcn_s_setprio(1);
    #pragma unroll
    for (int mi = 0; mi < 2; ++mi)
      #pragma unroll
      for (int nr = 0; nr < 4; ++nr)
        #pragma unroll
        for (int ks = 0; ks < 2; ++ks)
          mfma16(acc[mi + 2][nr], af23[mi][ks], bf_[nr][ks]);
    __builtin_amdgcn_s_setprio(0);
    if (more) asm volatile("s_waitcnt vmcnt(0)" ::: "memory");
    __builtin_amdgcn_s_barrier();
  }
  #undef STA
  #undef STB

  #pragma unroll
  for (int nr = 0; nr < 4; ++nr) {
    const int col = n0 + wn + nr * 16 + l15;
    #pragma unroll
    for (int mr = 0; mr < 4; ++mr)
      gemm_epi<MODE>(acc[mr][nr], m0 + wm + mr * 16 + kg * 4, col, N,
                     bias0, bias1, bias2, outF, o0, o1, o2);
  }
}

// ---------------- causal flash attention (swapped-operand, 8-wave 128-row tiles) ----------------
// r14-exact. grid (8, B*H), 512 threads; block x -> q-tiles {x, 15-x} (uniform 36
// KV-iters; per-CU aggregate balance); wave owns 16 q-rows; 8 waves share each staged
// 64-row K/V tile. T1 XCD swizzle: work = head*8 + qpair -> 8 heads/XCD = 4MB KV in
// that XCD's L2 (FETCH 147->25MB). T13 defer-max; exp2 w/ log2e prefolded.
__global__ __launch_bounds__(512) void attn_k(const unsigned short* __restrict__ q,
                                              const unsigned short* __restrict__ k,
                                              const unsigned short* __restrict__ vt,
                                              unsigned short* __restrict__ concat) {
  __shared__ __align__(16) unsigned short Ks[64 * 64];      // [k-row][d], xor-swizzled
  __shared__ __align__(16) unsigned short Vs[64 * 64];      // [d][k-col], xor-swizzled
  __shared__ __align__(16) unsigned short PL[8][16 * 72];   // per-wave P, stride 72 bf16

  const int tid = threadIdx.x, wid = tid >> 6, lane = tid & 63;
  const int l15 = lane & 15, kg = lane >> 4;
  const unsigned work = xcd_work(blockIdx.y * 8 + blockIdx.x, 512);
  const int qxi = work & 7, bh = (int)(work >> 3);
  const int b = bh >> 4, h = bh & 15;

  const char* kb = (const char*)(k + (size_t)bh * SS * DHH);
  const char* vb = (const char*)(vt + (size_t)bh * DHH * SS);
  unsigned short* ob = concat + (size_t)b * SS * DD + h * DHH;

  const int srow = wid * 8 + (lane >> 3);                    // staged row (8/wave)
  const int swz_c = ((lane & 7) * 16) ^ ((lane >> 3) << 4);  // pre-swizzled source byte col
  const int swr = (l15 & 7) << 4;                            // read-side row xor (byte)
  unsigned short* pl = &PL[wid][0];

  #pragma unroll 1
  for (int half = 0; half < 2; ++half) {
    const int qt = (half == 0) ? qxi : 15 - qxi;
    const int q0 = qt * 128;
    const int q0w = q0 + wid * 16;
    const unsigned short* qb = q + ((size_t)bh * SS + q0w) * DHH;
    const int qrow = q0w + l15;

    v8bf qf[2];
    #pragma unroll
    for (int ks = 0; ks < 2; ++ks)
      qf[ks] = *(const v8bf*)&qb[l15 * DHH + ks * 32 + kg * 8];

    v4f acc[4] = {};
    float mrun = -1e30f, ssum = 0.f;

    const int T = qt * 2 + 2;
    for (int it = 0; it < T; ++it) {
      const int t0 = it * 64;
      gload16(kb + (size_t)(t0 + srow) * 128 + swz_c, &Ks[(wid * 8) * 64]);
      gload16(vb + (size_t)srow * 4096 + (size_t)t0 * 2 + swz_c, &Vs[(wid * 8) * 64]);
      __syncthreads();   // vmcnt drained: K/V tile resident

      if (t0 <= q0w + 15) {   // wave-uniform compute guard (no barrier inside)
        v4f sT[4] = {};
        #pragma unroll
        for (int mt = 0; mt < 4; ++mt) {
          #pragma unroll
          for (int ks = 0; ks < 2; ++ks) {
            const v8bf kf = *(const v8bf*)((const char*)Ks + (mt * 16 + l15) * 128 +
                                           ((ks * 64 + kg * 16) ^ swr));
            mfma16(sT[mt], kf, qf[ks]);
          }
        }

        const bool full = (t0 + 63 <= q0w);
        float p[16];
        #pragma unroll
        for (int mt = 0; mt < 4; ++mt)
          #pragma unroll
          for (int rg = 0; rg < 4; ++rg) {
            float s = sT[mt][rg];
            if (!full) s = (t0 + mt * 16 + kg * 4 + rg <= qrow) ? s : -1e30f;
            p[mt * 4 + rg] = s;
          }
        float m8[8], m4_[4];
        #pragma unroll
        for (int i = 0; i < 8; ++i) m8[i] = fmaxf(p[2 * i], p[2 * i + 1]);
        #pragma unroll
        for (int i = 0; i < 4; ++i) m4_[i] = fmaxf(m8[2 * i], m8[2 * i + 1]);
        float mx = fmaxf(fmaxf(m4_[0], m4_[1]), fmaxf(m4_[2], m4_[3]));
        mx = fmaxf(mx, __shfl_xor(mx, 16));
        mx = fmaxf(mx, __shfl_xor(mx, 32));
        if (!__all(mx - mrun <= 8.0f)) {   // T13 defer-max (exact: P <= 2^8, bf16-safe)
          const float mnew = fmaxf(mrun, mx);
          const float fac = exp2f(mrun - mnew);
          mrun = mnew;
          ssum *= fac;
          #pragma unroll
          for (int mt = 0; mt < 4; ++mt) acc[mt] *= fac;
        }
        #pragma unroll
        for (int i = 0; i < 16; ++i) p[i] = exp2f(p[i] - mrun);
        float s8[8], s4_[4];
        #pragma unroll
        for (int i = 0; i < 8; ++i) s8[i] = p[2 * i] + p[2 * i + 1];
        #pragma unroll
        for (int i = 0; i < 4; ++i) s4_[i] = s8[2 * i] + s8[2 * i + 1];
        float ts = (s4_[0] + s4_[1]) + (s4_[2] + s4_[3]);
        ts += __shfl_xor(ts, 16);
        ts += __shfl_xor(ts, 32);
        ssum += ts;
        #pragma unroll
        for (int mt = 0; mt < 4; ++mt) {
          uint2 w;
          w.x = bf2bits(__float22bfloat162_rn(make_float2(p[mt * 4 + 0], p[mt * 4 + 1])));
          w.y = bf2bits(__float22bfloat162_rn(make_float2(p[mt * 4 + 2], p[mt * 4 + 3])));
          *(uint2*)((char*)pl + l15 * 144 + mt * 32 + kg * 8) = w;
        }
        asm volatile("s_waitcnt lgkmcnt(0)" ::: "memory");   // P writes -> P reads (wave-local)
        __builtin_amdgcn_sched_barrier(0);

        #pragma unroll
        for (int ks = 0; ks < 2; ++ks) {
          const v8bf pb = *(const v8bf*)((const char*)pl + l15 * 144 + ks * 64 + kg * 16);
          #pragma unroll
          for (int mt = 0; mt < 4; ++mt) {
            const v8bf va = *(const v8bf*)((const char*)Vs + (mt * 16 + l15) * 128 +
                                           ((ks * 64 + kg * 16) ^ swr));
            mfma16(acc[mt], va, pb);
          }
        }
      }
      __syncthreads();   // all reads of Ks/Vs done before next stage overwrites
    }

    const float inv = 1.0f / ssum;
    #pragma unroll
    for (int mt = 0; mt < 4; ++mt) {
      ushort4 o4;
      o4.x = f2bf(acc[mt][0] * inv);
      o4.y = f2bf(acc[mt][1] * inv);
      o4.z = f2bf(acc[mt][2] * inv);
      o4.w = f2bf(acc[mt][3] * inv);
      *(ushort4*)&ob[(size_t)qrow * DD + mt * 16 + kg * 4] = o4;
    }
  }
}

// ---------------- fused residual + LayerNorm (bf16 residual chain) ----------------
// Both variants read bf16 a + bf16 t (r21: LN1 now reads XBF instead of f32 x —
// -16MB HBM; LN normalizes the ~2^-8 input rounding away).
// V=0 (LN1): writes bf16 y only. V=1 (LN2): writes f32 d_out.
template<int V>
__global__ __launch_bounds__(256) void resid_ln_k(const unsigned short* __restrict__ ab,
                                                  const unsigned short* __restrict__ t,
                                                  const float* __restrict__ sc,
                                                  const float* __restrict__ bi,
                                                  float* __restrict__ yo,
                                                  unsigned short* __restrict__ yb) {
  __shared__ float rs[4], rs2[4];
  const int row = blockIdx.x, tid = threadIdx.x;
  const int wid = tid >> 6, lane = tid & 63;
  const ushort4 u4 = ((const ushort4*)(ab + (size_t)row * DD))[tid];
  const ushort4 t4 = ((const ushort4*)(t + (size_t)row * DD))[tid];
  const float v0 = b2f(u4.x) + b2f(t4.x), v1 = b2f(u4.y) + b2f(t4.y);
  const float v2 = b2f(u4.z) + b2f(t4.z), v3 = b2f(u4.w) + b2f(t4.w);
  float s = v0 + v1 + v2 + v3;
  float s2 = v0 * v0 + v1 * v1 + v2 * v2 + v3 * v3;
  #pragma unroll
  for (int m = 1; m < 64; m <<= 1) { s += __shfl_xor(s, m); s2 += __shfl_xor(s2, m); }
  if (lane == 0) { rs[wid] = s; rs2[wid] = s2; }
  __syncthreads();
  s = rs[0] + rs[1] + rs[2] + rs[3];
  s2 = rs2[0] + rs2[1] + rs2[2] + rs2[3];
  const float mu = s * (1.0f / DD);
  const float var = s2 * (1.0f / DD) - mu * mu;
  const float rstd = rsqrtf(var + 1e-5f);
  const int c0 = tid * 4;
  const float o0 = (v0 - mu) * rstd * sc[c0 + 0] + bi[c0 + 0];
  const float o1 = (v1 - mu) * rstd * sc[c0 + 1] + bi[c0 + 1];
  const float o2 = (v2 - mu) * rstd * sc[c0 + 2] + bi[c0 + 2];
  const float o3 = (v3 - mu) * rstd * sc[c0 + 3] + bi[c0 + 3];
  if constexpr (V == 0) {
    ushort4 ub; ub.x = f2bf(o0); ub.y = f2bf(o1); ub.z = f2bf(o2); ub.w = f2bf(o3);
    ((ushort4*)(yb + (size_t)row * DD))[tid] = ub;
  } else {
    float4 ov; ov.x = o0; ov.y = o1; ov.z = o2; ov.w = o3;
    ((float4*)(yo + (size_t)row * DD))[tid] = ov;
  }
}

// ---------------- launch ----------------

extern "C" void kernel_launch(void* const* d_in, const int* in_sizes, int n_in,
                              void* d_out, int out_size, void* d_ws, size_t ws_size,
                              hipStream_t stream) {
  const float* x   = (const float*)d_in[0];
  const float* wq  = (const float*)d_in[1];
  const float* bq  = (const float*)d_in[2];
  const float* wk  = (const float*)d_in[3];
  const float* bk  = (const float*)d_in[4];
  const float* wv  = (const float*)d_in[5];
  const float* bv  = (const float*)d_in[6];
  const float* wo  = (const float*)d_in[7];
  const float* bo  = (const float*)d_in[8];
  const float* l1s = (const float*)d_in[9];
  const float* l1b = (const float*)d_in[10];
  const float* w1  = (const float*)d_in[11];
  const float* b1  = (const float*)d_in[12];
  const float* w2  = (const float*)d_in[13];
  const float* b2  = (const float*)d_in[14];
  const float* l2s = (const float*)d_in[15];
  const float* l2b = (const float*)d_in[16];

  char* ws = (char*)d_ws;
  unsigned short* WO_T  = (unsigned short*)(ws + 0);          //  2 MiB [1024][1024]
  unsigned short* W1_T  = (unsigned short*)(ws + 2097152);    //  8 MiB [4096][1024]
  unsigned short* W2_T  = (unsigned short*)(ws + 10485760);   //  8 MiB [1024][4096]
  unsigned short* TMP1B = (unsigned short*)(ws + 18874368);   // 16 MiB bf16 attn_out
  unsigned short* TMP2B = (unsigned short*)(ws + 35651584);   // 16 MiB bf16 ff_out
  unsigned short* YBF   = (unsigned short*)(ws + 52428800);   // 16 MiB bf16 y
  unsigned short* XBF   = (unsigned short*)(ws + 102760448);  // 16 MiB
  unsigned short* WQKVT = (unsigned short*)(ws + 119537664);  //  6 MiB [3072][1024]
  unsigned short* QB    = (unsigned short*)(ws + 125829120);  // 16 MiB
  unsigned short* KB    = (unsigned short*)(ws + 142606336);  // 16 MiB
  unsigned short* VTB   = (unsigned short*)(ws + 159383552);  // 16 MiB
  unsigned short* CONC  = (unsigned short*)(ws + 176160768);  // 16 MiB (ends ~184 MiB)
  unsigned short* H1    = (unsigned short*)(ws + 102760448 + 16777216);  // 48 MiB?  NO —
  // H1 must be 64 MiB; alias WQKVT..CONC region is unsafe (WQKVT/CONC still live).
  // Keep r14 aliasing: H1 aliases XBF..VTB (dead after attention+LN1 read XBF).
  H1 = (unsigned short*)(ws + 102760448);   // 64 MiB, aliases XBF..VTB

  constexpr int GSMEM  = 131072;   // wide: A 64K + B 64K
  constexpr int GSMEMN = 98304;    // narrow: A 64K + B 32K
  hipFuncSetAttribute(reinterpret_cast<const void*>(gemm_bt<2>),
                      hipFuncAttributeMaxDynamicSharedMemorySize, GSMEM);
  hipFuncSetAttribute(reinterpret_cast<const void*>(gemm_bt_n<0>),
                      hipFuncAttributeMaxDynamicSharedMemorySize, GSMEMN);
  hipFuncSetAttribute(reinterpret_cast<const void*>(gemm_bt_n<1>),
                      hipFuncAttributeMaxDynamicSharedMemorySize, GSMEMN);
  hipFuncSetAttribute(reinterpret_cast<const void*>(gemm_bt_n<3>),
                      hipFuncAttributeMaxDynamicSharedMemorySize, GSMEMN);

  pack_x_k<<<8192, 256, 0, stream>>>(x, XBF);
  transpose_qkv_k<<<dim3(2, 32, 48), dim3(32, 8), 0, stream>>>(wq, wk, wv, WQKVT);
  transpose_k<<<dim3(32, 32),  dim3(32, 8), 0, stream>>>(wo, WO_T, 1024, 1024);
  transpose_k<<<dim3(128, 32), dim3(32, 8), 0, stream>>>(w1, W1_T, 1024, 4096);
  transpose_k<<<dim3(32, 128), dim3(32, 8), 0, stream>>>(w2, W2_T, 4096, 1024);

  gemm_bt_n<0><<<dim3(24, 32), 512, GSMEMN, stream>>>(XBF, WQKVT, bq, bk, bv,
      nullptr, QB, KB, VTB, MROWS, 3072, 1024);
  attn_k<<<dim3(8, 64), 512, 0, stream>>>(QB, KB, VTB, CONC);
  gemm_bt_n<1><<<dim3(8, 32), 512, GSMEMN, stream>>>(CONC, WO_T, bo, nullptr, nullptr,
      nullptr, TMP1B, nullptr, nullptr, MROWS, 1024, 1024);
  resid_ln_k<0><<<8192, 256, 0, stream>>>(XBF, TMP1B, l1s, l1b, nullptr, YBF);
  gemm_bt<2><<<dim3(16, 32), 512, GSMEM, stream>>>(YBF, W1_T, b1, nullptr, nullptr,
      nullptr, H1, nullptr, nullptr, MROWS, 4096, 1024);
  gemm_bt_n<3><<<dim3(8, 32), 512, GSMEMN, stream>>>(H1, W2_T, b2, nullptr, nullptr,
      nullptr, TMP2B, nullptr, nullptr, MROWS, 1024, 4096);
  resid_ln_k<1><<<8192, 256, 0, stream>>>(YBF, TMP2B, l2s, l2b,
      (float*)d_out, nullptr);
}

// Round 22
// 377.746 us; speedup vs baseline: 1.0103x; 1.0103x over previous
//
#include <hip/hip_runtime.h>
#include <hip/hip_bf16.h>
#include <cstdint>

#define BB 4
#define SS 2048
#define DD 1024
#define HH 16
#define DHH 64
#define DFFN 4096
#define MROWS (BB*SS)   // 8192

typedef __attribute__((ext_vector_type(8))) __bf16 v8bf;  // MFMA A/B operand (4 VGPRs)
typedef __attribute__((ext_vector_type(4))) float v4f;    // MFMA acc

static __device__ __forceinline__ unsigned short f2bf(float f) {
  unsigned u = __float_as_uint(f);
  u = (u + 0x7fffu + ((u >> 16) & 1u)) >> 16;  // RNE
  return (unsigned short)u;
}

static __device__ __forceinline__ float b2f(unsigned short u) {
  return __uint_as_float((unsigned)u << 16);
}

static __device__ __forceinline__ unsigned bf2bits(__hip_bfloat162 h) {
  union { __hip_bfloat162 h; unsigned u; } cv; cv.h = h; return cv.u;
}

// D = A(16x32)*B(32x16)+D. A-frag: lane holds A[lane&15][8*(lane>>4)+i];
// B-frag: B[8*(lane>>4)+i][lane&15]; D: col=lane&15, row=(lane>>4)*4+reg (m89-verified)
static __device__ __forceinline__ void mfma16(v4f& d, v8bf a, v8bf b) {
  d = __builtin_amdgcn_mfma_f32_16x16x32_bf16(a, b, d, 0, 0, 0);
}

// async global->LDS, 16B per lane; LDS dest = wave-uniform base + lane*16
static __device__ __forceinline__ void gload16(const void* g, void* l) {
  __builtin_amdgcn_global_load_lds(
      (const __attribute__((address_space(1))) unsigned int*)(unsigned long long)g,
      (__attribute__((address_space(3))) unsigned int*)(unsigned int)(unsigned long long)l,
      16, 0, 0);
}

// T1 XCD swizzle: hw dispatch index -> work id so each XCD (hw%8 under round-robin)
// gets a CONTIGUOUS work chunk (m204 bijective form; all our grids are %8==0).
// REGISTER MODEL (r16): unified VGPR pool = 512/SIMD; (512,N) caps waves at 512/N regs.
// SCHEDULE MODEL (r18): keep both GEMM operands double-buffered (stage >=1 phase
// before drain); single-buffering inserts an uncovered stall.
static __device__ __forceinline__ unsigned xcd_work(unsigned hw, unsigned nwg) {
  return (hw & 7u) * (nwg >> 3) + (hw >> 3);
}

// ---------------- prep kernels ----------------

__global__ __launch_bounds__(256) void pack_x_k(const float* __restrict__ x,
                                                unsigned short* __restrict__ xb) {
  int i = blockIdx.x * 256 + threadIdx.x;           // one float4 per thread
  float4 v = ((const float4*)x)[i];
  ushort4 o;
  o.x = f2bf(v.x); o.y = f2bf(v.y); o.z = f2bf(v.z); o.w = f2bf(v.w);
  ((ushort4*)xb)[i] = o;
}

// dst[c][r] = bf16(src[r][c]); src is R x C row-major, dst is C x R row-major
static __device__ __forceinline__ void transpose_tile(const float* __restrict__ src,
                                                      unsigned short* __restrict__ dst,
                                                      int R, int C, int rt, int ct) {
  __shared__ float tile[32][33];
  const int tx = threadIdx.x, ty = threadIdx.y;
  #pragma unroll
  for (int j = 0; j < 4; ++j)
    tile[ty + j * 8][tx] = src[(size_t)(rt + ty + j * 8) * C + ct + tx];
  __syncthreads();
  #pragma unroll
  for (int j = 0; j < 4; ++j)
    dst[(size_t)(ct + ty + j * 8) * R + rt + tx] = f2bf(tile[tx][ty + j * 8]);
}

__global__ __launch_bounds__(256) void transpose_k(const float* __restrict__ src,
                                                   unsigned short* __restrict__ dst,
                                                   int R, int C) {
  transpose_tile(src, dst, R, C, blockIdx.y * 32, blockIdx.x * 32);
}

// wq/wk/wv are [H][D][DH]; packed dst row c = w*1024 + h*64 + e, cols = d (K-contig)
__global__ __launch_bounds__(256) void transpose_qkv_k(const float* __restrict__ wq,
                                                       const float* __restrict__ wk,
                                                       const float* __restrict__ wv,
                                                       unsigned short* __restrict__ dst) {
  const int z = blockIdx.z;
  const int w = z >> 4, h = z & 15;
  const float* src = (w == 0) ? wq : ((w == 1) ? wk : wv);
  src += (size_t)h * DD * DHH;
  unsigned short* d = dst + (size_t)(w * DD + h * DHH) * DD;
  transpose_tile(src, d, DD, DHH, blockIdx.y * 32, blockIdx.x * 32);
}

// ---------------- shared GEMM epilogue ----------------
// MODE 1 (O-proj) and MODE 3 (FF2) emit bf16 residual terms (o0) — LN accumulates
// in f32; input perturbation ~2^-8 is normalized away (r20-validated).
template<int MODE>
static __device__ __forceinline__ void gemm_epi(
    const v4f& a4, int rb, int col, int N,
    const float* __restrict__ bias0, const float* __restrict__ bias1,
    const float* __restrict__ bias2,
    float* __restrict__ outF, unsigned short* __restrict__ o0,
    unsigned short* __restrict__ o1, unsigned short* __restrict__ o2) {
  if constexpr (MODE == 0) {
    const int seg = col >> 10, cc = col & 1023;
    const int h = cc >> 6, e = cc & 63;
    const float bias = (seg == 0) ? bias0[cc] : (seg == 1) ? bias1[cc] : bias2[cc];
    if (seg < 2) {           // q or k -> [B,H,S,DH]; q pre-scaled by log2e/8
      unsigned short* dst = (seg == 0) ? o0 : o1;
      const float scl = (seg == 0) ? 0.18033688f : 1.0f;   // 0.125 * log2(e)
      #pragma unroll
      for (int i = 0; i < 4; ++i) {
        const int row = rb + i, b = row >> 11, s = row & (SS - 1);
        dst[(((size_t)b * HH + h) * SS + s) * DHH + e] = f2bf((a4[i] + bias) * scl);
      }
    } else {                 // v -> transposed [B,H,DH,S]
      const int b = rb >> 11, s0q = rb & (SS - 1);
      ushort4 pv;
      pv.x = f2bf(a4[0] + bias);
      pv.y = f2bf(a4[1] + bias);
      pv.z = f2bf(a4[2] + bias);
      pv.w = f2bf(a4[3] + bias);
      *(ushort4*)&o2[(((size_t)b * HH + h) * DHH + e) * SS + s0q] = pv;
    }
  } else if constexpr (MODE == 1 || MODE == 3) {   // bf16 residual term
    const float bias = bias0[col];
    #pragma unroll
    for (int i = 0; i < 4; ++i)
      o0[(size_t)(rb + i) * N + col] = f2bf(a4[i] + bias);
  } else {  // MODE 2: relu -> bf16
    const float bias = bias0[col];
    #pragma unroll
    for (int i = 0; i < 4; ++i)
      o0[(size_t)(rb + i) * N + col] = f2bf(fmaxf(a4[i] + bias, 0.f));
  }
}

// ---------------- wide GEMM: 256x256, BK=64, 8 waves 2Mx4N (r9/r12/r14-validated) ----------------

template<int MODE>
__global__ __launch_bounds__(512, 2) void gemm_bt(
    const unsigned short* __restrict__ A, const unsigned short* __restrict__ Bt,
    const float* __restrict__ bias0, const float* __restrict__ bias1,
    const float* __restrict__ bias2,
    float* __restrict__ outF, unsigned short* __restrict__ o0,
    unsigned short* __restrict__ o1, unsigned short* __restrict__ o2,
    int M, int N, int K) {
  extern __shared__ __align__(16) char smem[];   // A 2x32K | B 2x32K
  const int tid = threadIdx.x;
  const int wid = tid >> 6, lane = tid & 63;
  const int l15 = lane & 15, kg = lane >> 4;
  const unsigned nwg = gridDim.x * gridDim.y;
  const unsigned work = xcd_work(blockIdx.y * gridDim.x + blockIdx.x, nwg);
  const int m0 = (int)(work / gridDim.x) * 256, n0 = (int)(work % gridDim.x) * 256;
  const int wm = (wid >> 2) * 128, wn = (wid & 3) * 64;

  const int sr8 = wid * 8 + (lane >> 3);
  const int sge = ((lane & 7) ^ ((lane >> 3) & 7)) << 3;
  const int swr = (l15 & 7) << 4;

  const int NK = K >> 6;
  v4f acc[8][4] = {};

  #define STA(q, kt, lb) gload16(A  + (size_t)(m0 + (q) * 64 + sr8) * K + (kt) * 64 + sge, \
                                 (lb) + (q) * 8192 + wid * 1024)
  #define STB(q, kt, lb) gload16(Bt + (size_t)(n0 + (q) * 64 + sr8) * K + (kt) * 64 + sge, \
                                 (lb) + (q) * 8192 + wid * 1024)

  {  // prologue
    char* A0b = smem;
    char* B0b = smem + 65536;
    STB(0, 0, B0b); STB(1, 0, B0b); STB(2, 0, B0b); STB(3, 0, B0b);
    STA(0, 0, A0b); STA(2, 0, A0b); STA(1, 0, A0b); STA(3, 0, A0b);
    asm volatile("s_waitcnt vmcnt(2)" ::: "memory");
    __builtin_amdgcn_s_barrier();
  }

  #pragma unroll 1
  for (int j = 0; j < NK; ++j) {
    char* Ac = smem + (j & 1) * 32768;
    char* Bc = smem + 65536 + (j & 1) * 32768;
    char* An = smem + ((j + 1) & 1) * 32768;
    char* Bn = smem + 65536 + ((j + 1) & 1) * 32768;
    const bool more = (j + 1 < NK);

    v8bf bf_[4][2], af01[4][2];
    #pragma unroll
    for (int nr = 0; nr < 4; ++nr)
      #pragma unroll
      for (int ks = 0; ks < 2; ++ks)
        bf_[nr][ks] = *(const v8bf*)(Bc + (wn + nr * 16 + l15) * 128 +
                                     (((ks * 4 + kg) << 4) ^ swr));
    #pragma unroll
    for (int mi = 0; mi < 4; ++mi)
      #pragma unroll
      for (int ks = 0; ks < 2; ++ks)
        af01[mi][ks] = *(const v8bf*)(Ac + (wm + mi * 16 + l15) * 128 +
                                      (((ks * 4 + kg) << 4) ^ swr));
    if (more) { STB(0, j + 1, Bn); STB(1, j + 1, Bn); STB(2, j + 1, Bn); STB(3, j + 1, Bn); }
    __builtin_amdgcn_s_setprio(1);
    #pragma unroll
    for (int mi = 0; mi < 2; ++mi)
      #pragma unroll
      for (int nr = 0; nr < 4; ++nr)
        #pragma unroll
        for (int ks = 0; ks < 2; ++ks)
          mfma16(acc[mi][nr], af01[mi][ks], bf_[nr][ks]);
    __builtin_amdgcn_s_setprio(0);
    __builtin_amdgcn_s_barrier();

    if (more) {
      STA(0, j + 1, An); STA(2, j + 1, An); STA(1, j + 1, An); STA(3, j + 1, An);
      asm volatile("s_waitcnt vmcnt(8)" ::: "memory");
    } else {
      asm volatile("s_waitcnt vmcnt(0)" ::: "memory");
    }
    __builtin_amdgcn_s_setprio(1);
    #pragma unroll
    for (int mi = 2; mi < 4; ++mi)
      #pragma unroll
      for (int nr = 0; nr < 4; ++nr)
        #pragma unroll
        for (int ks = 0; ks < 2; ++ks)
          mfma16(acc[mi][nr], af01[mi][ks], bf_[nr][ks]);
    __builtin_amdgcn_s_setprio(0);
    __builtin_amdgcn_s_barrier();

    v8bf af23[4][2];
    #pragma unroll
    for (int mi = 0; mi < 4; ++mi)
      #pragma unroll
      for (int ks = 0; ks < 2; ++ks)
        af23[mi][ks] = *(const v8bf*)(Ac + (wm + (mi + 4) * 16 + l15) * 128 +
                                      (((ks * 4 + kg) << 4) ^ swr));
    __builtin_amdgcn_s_setprio(1);
    #pragma unroll
    for (int mi = 0; mi < 2; ++mi)
      #pragma unroll
      for (int nr = 0; nr < 4; ++nr)
        #pragma unroll
        for (int ks = 0; ks < 2; ++ks)
          mfma16(acc[mi + 4][nr], af23[mi][ks], bf_[nr][ks]);
    __builtin_amdgcn_s_setprio(0);
    __builtin_amdgcn_s_barrier();

    if (more) asm volatile("s_waitcnt vmcnt(2)" ::: "memory");
    __builtin_amdgcn_s_setprio(1);
    #pragma unroll
    for (int mi = 2; mi < 4; ++mi)
      #pragma unroll
      for (int nr = 0; nr < 4; ++nr)
        #pragma unroll
        for (int ks = 0; ks < 2; ++ks)
          mfma16(acc[mi + 4][nr], af23[mi][ks], bf_[nr][ks]);
    __builtin_amdgcn_s_setprio(0);
    __builtin_amdgcn_s_barrier();
  }
  #undef STA
  #undef STB

  #pragma unroll
  for (int nr = 0; nr < 4; ++nr) {
    const int col = n0 + wn + nr * 16 + l15;
    #pragma unroll
    for (int mr = 0; mr < 8; ++mr)
      gemm_epi<MODE>(acc[mr][nr], m0 + wm + mr * 16 + kg * 4, col, N,
                     bias0, bias1, bias2, outF, o0, o1, o2);
  }
}

// ---------------- narrow GEMM: 256x128, BK=64, 8 waves 4Mx2N (r10/r12/r14-validated) ----------------

template<int MODE>
__global__ __launch_bounds__(512, 2) void gemm_bt_n(
    const unsigned short* __restrict__ A, const unsigned short* __restrict__ Bt,
    const float* __restrict__ bias0, const float* __restrict__ bias1,
    const float* __restrict__ bias2,
    float* __restrict__ outF, unsigned short* __restrict__ o0,
    unsigned short* __restrict__ o1, unsigned short* __restrict__ o2,
    int M, int N, int K) {
  extern __shared__ __align__(16) char smem[];   // A 2x32K @0 | B 2x16K @65536
  const int tid = threadIdx.x;
  const int wid = tid >> 6, lane = tid & 63;
  const int l15 = lane & 15, kg = lane >> 4;
  const unsigned nwg = gridDim.x * gridDim.y;
  const unsigned work = xcd_work(blockIdx.y * gridDim.x + blockIdx.x, nwg);
  const int m0 = (int)(work / gridDim.x) * 256, n0 = (int)(work % gridDim.x) * 128;
  const int wm = (wid >> 1) * 64, wn = (wid & 1) * 64;

  const int sr8 = wid * 8 + (lane >> 3);
  const int sge = ((lane & 7) ^ ((lane >> 3) & 7)) << 3;
  const int swr = (l15 & 7) << 4;

  const int NK = K >> 6;
  v4f acc[4][4] = {};

  #define STA(q, kt, lb) gload16(A  + (size_t)(m0 + (q) * 64 + sr8) * K + (kt) * 64 + sge, \
                                 (lb) + (q) * 8192 + wid * 1024)
  #define STB(q, kt, lb) gload16(Bt + (size_t)(n0 + (q) * 64 + sr8) * K + (kt) * 64 + sge, \
                                 (lb) + (q) * 8192 + wid * 1024)

  {  // prologue: kt0 into buf0, full drain
    char* A0b = smem;
    char* B0b = smem + 65536;
    STB(0, 0, B0b); STB(1, 0, B0b);
    STA(0, 0, A0b); STA(1, 0, A0b); STA(2, 0, A0b); STA(3, 0, A0b);
    asm volatile("s_waitcnt vmcnt(0)" ::: "memory");
    __builtin_amdgcn_s_barrier();
  }

  #pragma unroll 1
  for (int j = 0; j < NK; ++j) {
    char* Ac = smem + (j & 1) * 32768;
    char* Bc = smem + 65536 + (j & 1) * 16384;
    char* An = smem + ((j + 1) & 1) * 32768;
    char* Bn = smem + 65536 + ((j + 1) & 1) * 16384;
    const bool more = (j + 1 < NK);

    // ---- p0 ----
    v8bf bf_[4][2], af01[2][2];
    #pragma unroll
    for (int nr = 0; nr < 4; ++nr)
      #pragma unroll
      for (int ks = 0; ks < 2; ++ks)
        bf_[nr][ks] = *(const v8bf*)(Bc + (wn + nr * 16 + l15) * 128 +
                                     (((ks * 4 + kg) << 4) ^ swr));
    #pragma unroll
    for (int mi = 0; mi < 2; ++mi)
      #pragma unroll
      for (int ks = 0; ks < 2; ++ks)
        af01[mi][ks] = *(const v8bf*)(Ac + (wm + mi * 16 + l15) * 128 +
                                      (((ks * 4 + kg) << 4) ^ swr));
    if (more) {
      STB(0, j + 1, Bn); STB(1, j + 1, Bn);
      STA(0, j + 1, An); STA(1, j + 1, An); STA(2, j + 1, An); STA(3, j + 1, An);
    }
    __builtin_amdgcn_s_setprio(1);
    #pragma unroll
    for (int mi = 0; mi < 2; ++mi)
      #pragma unroll
      for (int nr = 0; nr < 4; ++nr)
        #pragma unroll
        for (int ks = 0; ks < 2; ++ks)
          mfma16(acc[mi][nr], af01[mi][ks], bf_[nr][ks]);
    __builtin_amdgcn_s_setprio(0);
    __builtin_amdgcn_s_barrier();

    // ---- p1 ----
    v8bf af23[2][2];
    #pragma unroll
    for (int mi = 0; mi < 2; ++mi)
      #pragma unroll
      for (int ks = 0; ks < 2; ++ks)
        af23[mi][ks] = *(const v8bf*)(Ac + (wm + (mi + 2) * 16 + l15) * 128 +
                                      (((ks * 4 + kg) << 4) ^ swr));
    __builtin_amdgcn_s_setprio(1);
    #pragma unroll
    for (int mi = 0; mi < 2; ++mi)
      #pragma unroll
      for (int nr = 0; nr < 4; ++nr)
        #pragma unroll
        for (int ks = 0; ks < 2; ++ks)
          mfma16(acc[mi + 2][nr], af23[mi][ks], bf_[nr][ks]);
    __builtin_amdgcn_s_setprio(0);
    if (more) asm volatile("s_waitcnt vmcnt(0)" ::: "memory");
    __builtin_amdgcn_s_barrier();
  }
  #undef STA
  #undef STB

  #pragma unroll
  for (int nr = 0; nr < 4; ++nr) {
    const int col = n0 + wn + nr * 16 + l15;
    #pragma unroll
    for (int mr = 0; mr < 4; ++mr)
      gemm_epi<MODE>(acc[mr][nr], m0 + wm + mr * 16 + kg * 4, col, N,
                     bias0, bias1, bias2, outF, o0, o1, o2);
  }
}

// ---------------- causal flash attention (swapped-operand, 8-wave 128-row tiles) ----------------
// r14-exact. grid (8, B*H), 512 threads; block x -> q-tiles {x, 15-x} (uniform 36
// KV-iters; per-CU aggregate balance); wave owns 16 q-rows; 8 waves share each staged
// 64-row K/V tile. T1 XCD swizzle: work = head*8 + qpair -> 8 heads/XCD = 4MB KV in
// that XCD's L2 (FETCH 147->25MB). T13 defer-max; exp2 w/ log2e prefolded.
__global__ __launch_bounds__(512) void attn_k(const unsigned short* __restrict__ q,
                                              const unsigned short* __restrict__ k,
                                              const unsigned short* __restrict__ vt,
                                              unsigned short* __restrict__ concat) {
  __shared__ __align__(16) unsigned short Ks[64 * 64];      // [k-row][d], xor-swizzled
  __shared__ __align__(16) unsigned short Vs[64 * 64];      // [d][k-col], xor-swizzled
  __shared__ __align__(16) unsigned short PL[8][16 * 72];   // per-wave P, stride 72 bf16

  const int tid = threadIdx.x, wid = tid >> 6, lane = tid & 63;
  const int l15 = lane & 15, kg = lane >> 4;
  const unsigned work = xcd_work(blockIdx.y * 8 + blockIdx.x, 512);
  const int qxi = work & 7, bh = (int)(work >> 3);
  const int b = bh >> 4, h = bh & 15;

  const char* kb = (const char*)(k + (size_t)bh * SS * DHH);
  const char* vb = (const char*)(vt + (size_t)bh * DHH * SS);
  unsigned short* ob = concat + (size_t)b * SS * DD + h * DHH;

  const int srow = wid * 8 + (lane >> 3);                    // staged row (8/wave)
  const int swz_c = ((lane & 7) * 16) ^ ((lane >> 3) << 4);  // pre-swizzled source byte col
  const int swr = (l15 & 7) << 4;                            // read-side row xor (byte)
  unsigned short* pl = &PL[wid][0];

  #pragma unroll 1
  for (int half = 0; half < 2; ++half) {
    const int qt = (half == 0) ? qxi : 15 - qxi;
    const int q0 = qt * 128;
    const int q0w = q0 + wid * 16;
    const unsigned short* qb = q + ((size_t)bh * SS + q0w) * DHH;
    const int qrow = q0w + l15;

    v8bf qf[2];
    #pragma unroll
    for (int ks = 0; ks < 2; ++ks)
      qf[ks] = *(const v8bf*)&qb[l15 * DHH + ks * 32 + kg * 8];

    v4f acc[4] = {};
    float mrun = -1e30f, ssum = 0.f;

    const int T = qt * 2 + 2;
    for (int it = 0; it < T; ++it) {
      const int t0 = it * 64;
      gload16(kb + (size_t)(t0 + srow) * 128 + swz_c, &Ks[(wid * 8) * 64]);
      gload16(vb + (size_t)srow * 4096 + (size_t)t0 * 2 + swz_c, &Vs[(wid * 8) * 64]);
      __syncthreads();   // vmcnt drained: K/V tile resident

      if (t0 <= q0w + 15) {   // wave-uniform compute guard (no barrier inside)
        v4f sT[4] = {};
        #pragma unroll
        for (int mt = 0; mt < 4; ++mt) {
          #pragma unroll
          for (int ks = 0; ks < 2; ++ks) {
            const v8bf kf = *(const v8bf*)((const char*)Ks + (mt * 16 + l15) * 128 +
                                           ((ks * 64 + kg * 16) ^ swr));
            mfma16(sT[mt], kf, qf[ks]);
          }
        }

        const bool full = (t0 + 63 <= q0w);
        float p[16];
        #pragma unroll
        for (int mt = 0; mt < 4; ++mt)
          #pragma unroll
          for (int rg = 0; rg < 4; ++rg) {
            float s = sT[mt][rg];
            if (!full) s = (t0 + mt * 16 + kg * 4 + rg <= qrow) ? s : -1e30f;
            p[mt * 4 + rg] = s;
          }
        float m8[8], m4_[4];
        #pragma unroll
        for (int i = 0; i < 8; ++i) m8[i] = fmaxf(p[2 * i], p[2 * i + 1]);
        #pragma unroll
        for (int i = 0; i < 4; ++i) m4_[i] = fmaxf(m8[2 * i], m8[2 * i + 1]);
        float mx = fmaxf(fmaxf(m4_[0], m4_[1]), fmaxf(m4_[2], m4_[3]));
        mx = fmaxf(mx, __shfl_xor(mx, 16));
        mx = fmaxf(mx, __shfl_xor(mx, 32));
        if (!__all(mx - mrun <= 8.0f)) {   // T13 defer-max (exact: P <= 2^8, bf16-safe)
          const float mnew = fmaxf(mrun, mx);
          const float fac = exp2f(mrun - mnew);
          mrun = mnew;
          ssum *= fac;
          #pragma unroll
          for (int mt = 0; mt < 4; ++mt) acc[mt] *= fac;
        }
        #pragma unroll
        for (int i = 0; i < 16; ++i) p[i] = exp2f(p[i] - mrun);
        float s8[8], s4_[4];
        #pragma unroll
        for (int i = 0; i < 8; ++i) s8[i] = p[2 * i] + p[2 * i + 1];
        #pragma unroll
        for (int i = 0; i < 4; ++i) s4_[i] = s8[2 * i] + s8[2 * i + 1];
        float ts = (s4_[0] + s4_[1]) + (s4_[2] + s4_[3]);
        ts += __shfl_xor(ts, 16);
        ts += __shfl_xor(ts, 32);
        ssum += ts;
        #pragma unroll
        for (int mt = 0; mt < 4; ++mt) {
          uint2 w;
          w.x = bf2bits(__float22bfloat162_rn(make_float2(p[mt * 4 + 0], p[mt * 4 + 1])));
          w.y = bf2bits(__float22bfloat162_rn(make_float2(p[mt * 4 + 2], p[mt * 4 + 3])));
          *(uint2*)((char*)pl + l15 * 144 + mt * 32 + kg * 8) = w;
        }
        asm volatile("s_waitcnt lgkmcnt(0)" ::: "memory");   // P writes -> P reads (wave-local)
        __builtin_amdgcn_sched_barrier(0);

        #pragma unroll
        for (int ks = 0; ks < 2; ++ks) {
          const v8bf pb = *(const v8bf*)((const char*)pl + l15 * 144 + ks * 64 + kg * 16);
          #pragma unroll
          for (int mt = 0; mt < 4; ++mt) {
            const v8bf va = *(const v8bf*)((const char*)Vs + (mt * 16 + l15) * 128 +
                                           ((ks * 64 + kg * 16) ^ swr));
            mfma16(acc[mt], va, pb);
          }
        }
      }
      __syncthreads();   // all reads of Ks/Vs done before next stage overwrites
    }

    const float inv = 1.0f / ssum;
    #pragma unroll
    for (int mt = 0; mt < 4; ++mt) {
      ushort4 o4;
      o4.x = f2bf(acc[mt][0] * inv);
      o4.y = f2bf(acc[mt][1] * inv);
      o4.z = f2bf(acc[mt][2] * inv);
      o4.w = f2bf(acc[mt][3] * inv);
      *(ushort4*)&ob[(size_t)qrow * DD + mt * 16 + kg * 4] = o4;
    }
  }
}

// ---------------- fused residual + LayerNorm (bf16 residual chain) ----------------
// V=0 (LN1): a = f32 x, t = bf16 attn_out -> writes bf16 y only (fp32 Y dropped)
// V=1 (LN2): a = bf16 y, t = bf16 ff_out  -> writes f32 d_out
template<int V>
__global__ __launch_bounds__(256) void resid_ln_k(const float* __restrict__ af,
                                                  const unsigned short* __restrict__ ab,
                                                  const unsigned short* __restrict__ t,
                                                  const float* __restrict__ sc,
                                                  const float* __restrict__ bi,
                                                  float* __restrict__ yo,
                                                  unsigned short* __restrict__ yb) {
  __shared__ float rs[4], rs2[4];
  const int row = blockIdx.x, tid = threadIdx.x;
  const int wid = tid >> 6, lane = tid & 63;
  float a0, a1, a2, a3;
  if constexpr (V == 0) {
    const float4 x4 = ((const float4*)(af + (size_t)row * DD))[tid];
    a0 = x4.x; a1 = x4.y; a2 = x4.z; a3 = x4.w;
  } else {
    const ushort4 u4 = ((const ushort4*)(ab + (size_t)row * DD))[tid];
    a0 = b2f(u4.x); a1 = b2f(u4.y); a2 = b2f(u4.z); a3 = b2f(u4.w);
  }
  const ushort4 t4 = ((const ushort4*)(t + (size_t)row * DD))[tid];
  const float v0 = a0 + b2f(t4.x), v1 = a1 + b2f(t4.y);
  const float v2 = a2 + b2f(t4.z), v3 = a3 + b2f(t4.w);
  float s = v0 + v1 + v2 + v3;
  float s2 = v0 * v0 + v1 * v1 + v2 * v2 + v3 * v3;
  #pragma unroll
  for (int m = 1; m < 64; m <<= 1) { s += __shfl_xor(s, m); s2 += __shfl_xor(s2, m); }
  if (lane == 0) { rs[wid] = s; rs2[wid] = s2; }
  __syncthreads();
  s = rs[0] + rs[1] + rs[2] + rs[3];
  s2 = rs2[0] + rs2[1] + rs2[2] + rs2[3];
  const float mu = s * (1.0f / DD);
  const float var = s2 * (1.0f / DD) - mu * mu;
  const float rstd = rsqrtf(var + 1e-5f);
  const int c0 = tid * 4;
  const float o0 = (v0 - mu) * rstd * sc[c0 + 0] + bi[c0 + 0];
  const float o1 = (v1 - mu) * rstd * sc[c0 + 1] + bi[c0 + 1];
  const float o2 = (v2 - mu) * rstd * sc[c0 + 2] + bi[c0 + 2];
  const float o3 = (v3 - mu) * rstd * sc[c0 + 3] + bi[c0 + 3];
  if constexpr (V == 0) {
    ushort4 ub; ub.x = f2bf(o0); ub.y = f2bf(o1); ub.z = f2bf(o2); ub.w = f2bf(o3);
    ((ushort4*)(yb + (size_t)row * DD))[tid] = ub;
  } else {
    float4 ov; ov.x = o0; ov.y = o1; ov.z = o2; ov.w = o3;
    ((float4*)(yo + (size_t)row * DD))[tid] = ov;
  }
}

// ---------------- launch ----------------

extern "C" void kernel_launch(void* const* d_in, const int* in_sizes, int n_in,
                              void* d_out, int out_size, void* d_ws, size_t ws_size,
                              hipStream_t stream) {
  const float* x   = (const float*)d_in[0];
  const float* wq  = (const float*)d_in[1];
  const float* bq  = (const float*)d_in[2];
  const float* wk  = (const float*)d_in[3];
  const float* bk  = (const float*)d_in[4];
  const float* wv  = (const float*)d_in[5];
  const float* bv  = (const float*)d_in[6];
  const float* wo  = (const float*)d_in[7];
  const float* bo  = (const float*)d_in[8];
  const float* l1s = (const float*)d_in[9];
  const float* l1b = (const float*)d_in[10];
  const float* w1  = (const float*)d_in[11];
  const float* b1  = (const float*)d_in[12];
  const float* w2  = (const float*)d_in[13];
  const float* b2  = (const float*)d_in[14];
  const float* l2s = (const float*)d_in[15];
  const float* l2b = (const float*)d_in[16];

  char* ws = (char*)d_ws;
  unsigned short* WO_T  = (unsigned short*)(ws + 0);          //  2 MiB [1024][1024]
  unsigned short* W1_T  = (unsigned short*)(ws + 2097152);    //  8 MiB [4096][1024]
  unsigned short* W2_T  = (unsigned short*)(ws + 10485760);   //  8 MiB [1024][4096]
  unsigned short* TMP1B = (unsigned short*)(ws + 18874368);   // 16 MiB bf16 attn_out
  unsigned short* TMP2B = (unsigned short*)(ws + 35651584);   // 16 MiB bf16 ff_out
  unsigned short* YBF   = (unsigned short*)(ws + 52428800);   // 16 MiB bf16 y
  unsigned short* XBF   = (unsigned short*)(ws + 102760448);  // 16 MiB
  unsigned short* WQKVT = (unsigned short*)(ws + 119537664);  //  6 MiB [3072][1024]
  unsigned short* QB    = (unsigned short*)(ws + 125829120);  // 16 MiB
  unsigned short* KB    = (unsigned short*)(ws + 142606336);  // 16 MiB
  unsigned short* VTB   = (unsigned short*)(ws + 159383552);  // 16 MiB
  unsigned short* CONC  = (unsigned short*)(ws + 176160768);  // 16 MiB (ends ~184 MiB)
  unsigned short* H1    = (unsigned short*)(ws + 102760448);  // 64 MiB, aliases XBF..VTB (dead by then)

  constexpr int GSMEM  = 131072;   // wide: A 64K + B 64K
  constexpr int GSMEMN = 98304;    // narrow: A 64K + B 32K
  hipFuncSetAttribute(reinterpret_cast<const void*>(gemm_bt<2>),
                      hipFuncAttributeMaxDynamicSharedMemorySize, GSMEM);
  hipFuncSetAttribute(reinterpret_cast<const void*>(gemm_bt_n<0>),
                      hipFuncAttributeMaxDynamicSharedMemorySize, GSMEMN);
  hipFuncSetAttribute(reinterpret_cast<const void*>(gemm_bt_n<1>),
                      hipFuncAttributeMaxDynamicSharedMemorySize, GSMEMN);
  hipFuncSetAttribute(reinterpret_cast<const void*>(gemm_bt_n<3>),
                      hipFuncAttributeMaxDynamicSharedMemorySize, GSMEMN);

  pack_x_k<<<8192, 256, 0, stream>>>(x, XBF);
  transpose_qkv_k<<<dim3(2, 32, 48), dim3(32, 8), 0, stream>>>(wq, wk, wv, WQKVT);
  transpose_k<<<dim3(32, 32),  dim3(32, 8), 0, stream>>>(wo, WO_T, 1024, 1024);
  transpose_k<<<dim3(128, 32), dim3(32, 8), 0, stream>>>(w1, W1_T, 1024, 4096);
  transpose_k<<<dim3(32, 128), dim3(32, 8), 0, stream>>>(w2, W2_T, 4096, 1024);

  gemm_bt_n<0><<<dim3(24, 32), 512, GSMEMN, stream>>>(XBF, WQKVT, bq, bk, bv,
      nullptr, QB, KB, VTB, MROWS, 3072, 1024);
  attn_k<<<dim3(8, 64), 512, 0, stream>>>(QB, KB, VTB, CONC);
  gemm_bt_n<1><<<dim3(8, 32), 512, GSMEMN, stream>>>(CONC, WO_T, bo, nullptr, nullptr,
      nullptr, TMP1B, nullptr, nullptr, MROWS, 1024, 1024);
  resid_ln_k<0><<<8192, 256, 0, stream>>>(x, nullptr, TMP1B, l1s, l1b, nullptr, YBF);
  gemm_bt<2><<<dim3(16, 32), 512, GSMEM, stream>>>(YBF, W1_T, b1, nullptr, nullptr,
      nullptr, H1, nullptr, nullptr, MROWS, 4096, 1024);
  gemm_bt_n<3><<<dim3(8, 32), 512, GSMEMN, stream>>>(H1, W2_T, b2, nullptr, nullptr,
      nullptr, TMP2B, nullptr, nullptr, MROWS, 1024, 4096);
  resid_ln_k<1><<<8192, 256, 0, stream>>>(nullptr, YBF, TMP2B, l2s, l2b,
      (float*)d_out, nullptr);
}